// Round 1
// baseline (447.637 us; speedup 1.0000x reference)
//
#include <hip/hip_runtime.h>
#include <hip/hip_bf16.h>

// MHGCN: out = 0.5*(U1+U2), U1 = S@(feat@W1)+b1, U2 = S@(U1@W2)+b2,
// S = temp + temp^T, temp = einsum('ijk,kl->ij', A_stack, weight_b)
// N=8192, NFEAT=OUT=64.
//
// Pipeline:
//  1) k_sym_build: A_stack (1.34 GB, read once via upper-tri tile pairs) -> S bf16 [N][N] (ws)
//  2) k_small_gemm_t: feature@W1 -> H1t bf16 [64][N] (transposed for GEMM B staging)
//  3) k_gemm_skinny<0,0>: U1 = S@H1 + b1 (f32, ws), MFMA 16x16x32 bf16
//  4) k_small_gemm_t: U1@W2 -> H2t bf16 [64][N]
//  5) k_gemm_skinny<0,1>: out = 0.5*(U1 + S@H2 + b2)
// Fallback (<132 MB ws): k_gemm_skinny<1,*> recomputes S tiles from A_stack on the fly.

#define NN 8192

typedef __attribute__((ext_vector_type(8))) short short8;
typedef __attribute__((ext_vector_type(8))) unsigned short u16x8;
typedef __attribute__((ext_vector_type(4))) float f32x4;

static __device__ __forceinline__ unsigned short f2bf(float f) {
    unsigned u = __float_as_uint(f);
    u += 0x7FFFu + ((u >> 16) & 1u);     // round-to-nearest-even
    return (unsigned short)(u >> 16);
}

// ---------------------------------------------------------------------------
// 1) S = temp + temp^T  (bf16), upper-triangular 64x64 tile pairs, A read once
// ---------------------------------------------------------------------------
__global__ __launch_bounds__(256) void k_sym_build(
        const float* __restrict__ A, const float* __restrict__ wb,
        unsigned short* __restrict__ S) {
    __shared__ float Tt[64 * 65];   // +1 pad -> conflict-free transposed access

    int b = blockIdx.x;
    // decode linear id -> (bi, bj), bi <= bj, over NT=128 tiles
    double disc = 66049.0 - 8.0 * (double)b;     // (2*128+1)^2 - 8b
    int bi = (int)((257.0 - sqrt(disc)) * 0.5);
    if (bi < 0) bi = 0; if (bi > 127) bi = 127;
    while (bi < 127 && (bi + 1) * (257 - (bi + 1)) / 2 <= b) ++bi;
    while (bi > 0 && bi * (257 - bi) / 2 > b) --bi;
    int bj = bi + (b - bi * (257 - bi) / 2);

    const float w0 = wb[0], w1 = wb[1], w2 = wb[2], w3 = wb[3], w4 = wb[4];
    int t = threadIdx.x;
    int j = t & 63;        // col within tile (lane -> coalesced)
    int iw = t >> 6;       // wave id -> base row

    float t1[16];
    #pragma unroll
    for (int e = 0; e < 16; ++e) {
        int i = iw + e * 4;
        const float* p = A + ((long long)(bi * 64 + i) * NN + (bj * 64 + j)) * 5;
        t1[e] = p[0]*w0 + p[1]*w1 + p[2]*w2 + p[3]*w3 + p[4]*w4;
        const float* q = A + ((long long)(bj * 64 + i) * NN + (bi * 64 + j)) * 5;
        Tt[i * 65 + j] = q[0]*w0 + q[1]*w1 + q[2]*w2 + q[3]*w3 + q[4]*w4;
    }
    __syncthreads();
    float s[16];
    #pragma unroll
    for (int e = 0; e < 16; ++e) {
        int i = iw + e * 4;
        s[e] = t1[e] + Tt[j * 65 + i];    // S_tile[i][j] = T1[i][j] + T2[j][i]
        S[(long long)(bi * 64 + i) * NN + bj * 64 + j] = f2bf(s[e]);
    }
    __syncthreads();
    #pragma unroll
    for (int e = 0; e < 16; ++e) { int i = iw + e * 4; Tt[i * 65 + j] = s[e]; }
    __syncthreads();
    if (bi != bj) {
        #pragma unroll
        for (int e = 0; e < 16; ++e) {
            int i = iw + e * 4;
            // S[bj-tile][bi-tile] = S_tile^T
            S[(long long)(bj * 64 + i) * NN + bi * 64 + j] = f2bf(Tt[j * 65 + i]);
        }
    }
}

// ---------------------------------------------------------------------------
// 2/4) Yt[c][row] = sum_k X[row][k]*W[k][c]   (bf16, transposed output)
// ---------------------------------------------------------------------------
__global__ __launch_bounds__(256) void k_small_gemm_t(
        const float* __restrict__ X, const float* __restrict__ W,
        unsigned short* __restrict__ Yt) {
    __shared__ float Ys[64 * 65];
    int t = threadIdx.x, lane = t & 63, w = t >> 6;
    float wcol[64];                       // this lane's W column in registers
    #pragma unroll
    for (int k = 0; k < 64; ++k) wcol[k] = W[k * 64 + lane];
    int r0 = blockIdx.x * 64;
    for (int rr = 0; rr < 16; ++rr) {
        const float* x = X + (long long)(r0 + w * 16 + rr) * 64;
        float acc = 0.f;
        #pragma unroll
        for (int k = 0; k < 64; ++k) acc += x[k] * wcol[k];
        Ys[lane * 65 + w * 16 + rr] = acc;    // Ys[col][row-in-tile]
    }
    __syncthreads();
    #pragma unroll
    for (int e = 0; e < 16; ++e) {
        int elem = t + e * 256;
        int c = elem >> 6, jj = elem & 63;
        Yt[(long long)c * NN + r0 + jj] = f2bf(Ys[c * 65 + jj]);
    }
}

// ---------------------------------------------------------------------------
// 3/5) Y[i][f] = (FINAL? 0.5*(U1 + .) : .)(bias[f] + sum_j S[i][j]*H[j][f])
//      MFMA 16x16x32 bf16; Ts[16][128], Hst[64][128] in LDS, XOR-swizzled.
// ---------------------------------------------------------------------------
template<int SRC, int FINAL>
__global__ __launch_bounds__(256) void k_gemm_skinny(
        const unsigned short* __restrict__ S,
        const float* __restrict__ A, const float* __restrict__ wb,
        const unsigned short* __restrict__ Ht,   // [64][NN] bf16 (H transposed)
        const float* __restrict__ bias,
        const float* __restrict__ U1,            // used when FINAL==1
        float* __restrict__ Y) {
    __shared__ unsigned short TsU[16 * 128];
    __shared__ unsigned short HsU[64 * 128];
    int t = threadIdx.x, lane = t & 63, w = t >> 6;
    int i0 = blockIdx.x * 16;
    f32x4 acc = {0.f, 0.f, 0.f, 0.f};

    float w0 = 0.f, w1 = 0.f, w2 = 0.f, w3 = 0.f, w4 = 0.f;
    if (SRC == 1) { w0 = wb[0]; w1 = wb[1]; w2 = wb[2]; w3 = wb[3]; w4 = wb[4]; }

    const int si = t >> 4, sjc = (t & 15) * 8;   // Ts staging: row si, 8-col chunk
    const int hf = t >> 2, hcc = (t & 3) * 32;   // Hs staging: row hf, 32-col chunk
    const int row = lane & 15, kg = lane >> 4;
    const int hrow = w * 16 + row;

    for (int jt = 0; jt < NN; jt += 128) {
        __syncthreads();
        if (SRC == 0) {
            u16x8 v = *(const u16x8*)(S + (long long)(i0 + si) * NN + jt + sjc);
            *(u16x8*)((char*)TsU + (si * 256 + ((sjc * 2) ^ ((si & 7) << 4)))) = v;
        } else {
            u16x8 vout;
            #pragma unroll
            for (int q2 = 0; q2 < 8; ++q2) {
                int jj = sjc + q2;
                const float* p1 = A + ((long long)(i0 + si) * NN + jt + jj) * 5;
                const float* p2 = A + ((long long)(jt + jj) * NN + i0 + si) * 5;
                float v = p1[0]*w0 + p1[1]*w1 + p1[2]*w2 + p1[3]*w3 + p1[4]*w4
                        + p2[0]*w0 + p2[1]*w1 + p2[2]*w2 + p2[3]*w3 + p2[4]*w4;
                vout[q2] = f2bf(v);
            }
            *(u16x8*)((char*)TsU + (si * 256 + ((sjc * 2) ^ ((si & 7) << 4)))) = vout;
        }
        {
            const u16x8* hp = (const u16x8*)(Ht + (long long)hf * NN + jt + hcc);
            #pragma unroll
            for (int q = 0; q < 4; ++q) {
                u16x8 v = hp[q];
                *(u16x8*)((char*)HsU + (hf * 256 + (((hcc + q * 8) * 2) ^ ((hf & 7) << 4)))) = v;
            }
        }
        __syncthreads();
        #pragma unroll
        for (int kk = 0; kk < 4; ++kk) {
            short8 a = *(const short8*)((const char*)TsU +
                        (row * 256 + ((kk * 64 + kg * 16) ^ ((row & 7) << 4))));
            short8 bfrag = *(const short8*)((const char*)HsU +
                        (hrow * 256 + ((kk * 64 + kg * 16) ^ ((row & 7) << 4))));
            acc = __builtin_amdgcn_mfma_f32_16x16x32_bf16(a, bfrag, acc, 0, 0, 0);
        }
    }

    // D[m=4*(lane>>4)+r][n=lane&15]; n-tile per wave
    int r4 = lane >> 4;
    int f = w * 16 + row;
    float bv = bias[f];
    #pragma unroll
    for (int r = 0; r < 4; ++r) {
        long long i = i0 + r4 * 4 + r;
        float v = acc[r] + bv;
        if (FINAL) v = 0.5f * (U1[i * 64 + f] + v);
        Y[i * 64 + f] = v;
    }
}

// ---------------------------------------------------------------------------
extern "C" void kernel_launch(void* const* d_in, const int* in_sizes, int n_in,
                              void* d_out, int out_size, void* d_ws, size_t ws_size,
                              hipStream_t stream) {
    const float* A    = (const float*)d_in[0];
    const float* feat = (const float*)d_in[1];
    const float* wb   = (const float*)d_in[2];
    const float* W1   = (const float*)d_in[3];
    const float* b1   = (const float*)d_in[4];
    const float* W2   = (const float*)d_in[5];
    const float* b2   = (const float*)d_in[6];
    float* out = (float*)d_out;

    const size_t szS = (size_t)NN * NN * 2;       // 128 MB bf16 S
    const size_t szH = (size_t)64 * NN * 2;       // 1 MB  bf16 Ht
    const size_t szU = (size_t)NN * 64 * 4;       // 2 MB  f32  U1
    char* p = (char*)d_ws;
    bool fast = ws_size >= szS + 2 * szH + szU;

    unsigned short *S, *H1t, *H2t; float* U1;
    if (fast) {
        S   = (unsigned short*)p;
        H1t = (unsigned short*)(p + szS);
        H2t = (unsigned short*)(p + szS + szH);
        U1  = (float*)(p + szS + 2 * szH);
    } else {
        S   = nullptr;
        H1t = (unsigned short*)p;
        H2t = (unsigned short*)(p + szH);
        U1  = (float*)(p + 2 * szH);
    }

    if (fast) k_sym_build<<<8256, 256, 0, stream>>>(A, wb, S);
    k_small_gemm_t<<<128, 256, 0, stream>>>(feat, W1, H1t);
    if (fast) k_gemm_skinny<0, 0><<<512, 256, 0, stream>>>(S, A, wb, H1t, b1, nullptr, U1);
    else      k_gemm_skinny<1, 0><<<512, 256, 0, stream>>>(S, A, wb, H1t, b1, nullptr, U1);
    k_small_gemm_t<<<128, 256, 0, stream>>>(U1, W2, H2t);
    if (fast) k_gemm_skinny<0, 1><<<512, 256, 0, stream>>>(S, A, wb, H2t, b2, U1, out);
    else      k_gemm_skinny<1, 1><<<512, 256, 0, stream>>>(S, A, wb, H2t, b2, U1, out);
}